// Round 2
// baseline (4752.599 us; speedup 1.0000x reference)
//
#include <hip/hip_runtime.h>
#include <hip/hip_bf16.h>
#include <stdint.h>

// Decoder: 2-layer LSTM + Luong attention. input_feed=0 => attention fully
// deferred post-loop. Loop = lstm0+lstm1 per step with hi/lo-split h state
// (fp32-accurate A operand). ctxW / scores / final projection via 3-combo
// hi/lo split MFMA GEMMs; wc in fp32 VALU. c-state stays fp32 throughout.

typedef __bf16 bf16_t;
typedef __bf16 bf16x8 __attribute__((ext_vector_type(8)));
typedef __bf16 bf16x4 __attribute__((ext_vector_type(4)));
typedef float f32x4 __attribute__((ext_vector_type(4)));

#define AS1 __attribute__((address_space(1)))
#define AS3 __attribute__((address_space(3)))

__device__ __forceinline__ void gll16(const bf16_t* g, bf16_t* l) {
  __builtin_amdgcn_global_load_lds((const AS1 void*)g, (AS3 void*)l, 16, 0, 0);
}

__device__ __forceinline__ float sigm(float x){ return 1.f/(1.f+expf(-x)); }

// ---------------- prep kernels ----------------
__global__ void f2b(const float* __restrict__ in, bf16_t* __restrict__ outp, int n){
  int i = (blockIdx.x*256 + threadIdx.x)*4;
  if (i >= n) return;
  float4 v = *(const float4*)(in + i);
  bf16x4 o; o[0]=(bf16_t)v.x; o[1]=(bf16_t)v.y; o[2]=(bf16_t)v.z; o[3]=(bf16_t)v.w;
  *(bf16x4*)(outp + i) = o;
}

__global__ void f2b_pair(const float* __restrict__ in, bf16_t* __restrict__ oh,
                         bf16_t* __restrict__ ol, int n){
  int i = (blockIdx.x*256 + threadIdx.x)*4;
  if (i >= n) return;
  float4 v = *(const float4*)(in + i);
  float vv[4] = {v.x, v.y, v.z, v.w};
  bf16x4 h, l;
  #pragma unroll
  for (int j=0;j<4;j++){ h[j]=(bf16_t)vv[j]; l[j]=(bf16_t)(vv[j]-(float)h[j]); }
  *(bf16x4*)(oh + i) = h;
  *(bf16x4*)(ol + i) = l;
}

__global__ void bias_combine(const float* __restrict__ a, const float* __restrict__ b,
                             float* __restrict__ o, int n){
  int i = blockIdx.x*256 + threadIdx.x;
  if (i < n) o[i] = a[i] + b[i];
}

__global__ void embed_gather(const int* __restrict__ tokp, const float* __restrict__ embW,
                             bf16_t* __restrict__ xe){
  int m = blockIdx.x;
  int tokv = tokp[m];
  const float* src = embW + (size_t)tokv*1024 + threadIdx.x*4;
  float4 v = *(const float4*)src;
  bf16x4 o; o[0]=(bf16_t)v.x; o[1]=(bf16_t)v.y; o[2]=(bf16_t)v.z; o[3]=(bf16_t)v.w;
  *(bf16x4*)(xe + (size_t)m*1024 + threadIdx.x*4) = o;
}

// winT[e,d] = split(Win[d,e])
__global__ void transWin(const float* __restrict__ in, bf16_t* __restrict__ oh,
                         bf16_t* __restrict__ ol){
  __shared__ float t[32][33];
  int bi = blockIdx.x & 31, bj = blockIdx.x >> 5;
  int tx = threadIdx.x & 31, ty = threadIdx.x >> 5;  // 32 x 8
  #pragma unroll
  for (int i=0;i<4;i++){
    int d = bi*32 + ty + i*8, e = bj*32 + tx;
    t[ty+i*8][tx] = in[(size_t)d*1024 + e];
  }
  __syncthreads();
  #pragma unroll
  for (int i=0;i<4;i++){
    int e = bj*32 + ty + i*8, d = bi*32 + tx;
    float v = t[tx][ty+i*8];
    bf16_t h = (bf16_t)v;
    oh[(size_t)e*1024 + d] = h;
    ol[(size_t)e*1024 + d] = (bf16_t)(v - (float)h);
  }
}

// ---------------- plain bf16 GEMM (x0g): C = A@B^T + bias, out bf16 ----------------
__global__ __launch_bounds__(256) void gemm_bt(
    const bf16_t* __restrict__ A, const bf16_t* __restrict__ Bm,
    const float* __restrict__ bias, bf16_t* __restrict__ Cout,
    int M, int N, int K, int nTN)
{
  __shared__ bf16_t sA[128*64];
  __shared__ bf16_t sB[128*64];
  int tid = threadIdx.x, lane = tid & 63, w = tid >> 6;
  int tm = blockIdx.x / nTN, tn = blockIdx.x % nTN;
  int row0 = tm*128, col0 = tn*128;
  int wr = w >> 1, wcc = w & 1;
  f32x4 acc[4][4] = {};
  for (int kt = 0; kt < K; kt += 64) {
    __syncthreads();
    #pragma unroll
    for (int i=0;i<4;i++){
      int c = i*256 + tid;
      int r = c >> 3, kk = (c & 7) << 3;
      gll16(A  + (size_t)(row0+r)*K + kt + kk, sA + (size_t)(i*256 + w*64)*8);
      gll16(Bm + (size_t)(col0+r)*K + kt + kk, sB + (size_t)(i*256 + w*64)*8);
    }
    __syncthreads();
    #pragma unroll
    for (int kk=0;kk<64;kk+=32){
      bf16x8 av[4], bv[4];
      #pragma unroll
      for (int m=0;m<4;m++) av[m] = *(const bf16x8*)(sA + (wr*64 + m*16 + (lane&15))*64 + kk + ((lane>>4)<<3));
      #pragma unroll
      for (int n=0;n<4;n++) bv[n] = *(const bf16x8*)(sB + (wcc*64 + n*16 + (lane&15))*64 + kk + ((lane>>4)<<3));
      #pragma unroll
      for (int m=0;m<4;m++)
        #pragma unroll
        for (int n=0;n<4;n++)
          acc[m][n] = __builtin_amdgcn_mfma_f32_16x16x32_bf16(av[m], bv[n], acc[m][n], 0,0,0);
    }
  }
  #pragma unroll
  for (int n=0;n<4;n++){
    int cn = col0 + wcc*64 + n*16 + (lane & 15);
    float bvv = bias[cn];
    #pragma unroll
    for (int m=0;m<4;m++){
      int rm = row0 + wr*64 + m*16 + ((lane>>4)<<2);
      #pragma unroll
      for (int r=0;r<4;r++)
        Cout[(size_t)(rm+r)*N + cn] = (bf16_t)(acc[m][n][r] + bvv);
    }
  }
}

// ---------------- split GEMM: hi/lo A (two K-parts) x hi/lo B, 3 combos ----------------
template<int ACT_TANH, int OUT_PAIR>
__global__ __launch_bounds__(256) void gemm_split(
    const bf16_t* __restrict__ Ah1, const bf16_t* __restrict__ Al1,
    const bf16_t* __restrict__ Ah2, const bf16_t* __restrict__ Al2, int K1,
    const bf16_t* __restrict__ Bh, const bf16_t* __restrict__ Bl,
    float* __restrict__ Cf, bf16_t* __restrict__ Ch, bf16_t* __restrict__ Cl,
    int M, int N, int K, int nTN)
{
  __shared__ bf16_t sAh[128*64], sAl[128*64], sBh[128*64], sBl[128*64];
  int tid = threadIdx.x, lane = tid & 63, w = tid >> 6;
  int tm = blockIdx.x / nTN, tn = blockIdx.x % nTN;
  int row0 = tm*128, col0 = tn*128;
  int wr = w >> 1, wcc = w & 1;
  f32x4 acc[4][4] = {};
  for (int kt = 0; kt < K; kt += 64) {
    const bf16_t *Ah, *Al; int kl;
    if (kt < K1){ Ah=Ah1; Al=Al1; kl=kt; } else { Ah=Ah2; Al=Al2; kl=kt-K1; }
    __syncthreads();
    #pragma unroll
    for (int i=0;i<4;i++){
      int c = i*256 + tid;
      int r = c >> 3, kk = (c & 7) << 3;
      gll16(Ah + (size_t)(row0+r)*K1 + kl + kk, sAh + (size_t)(i*256 + w*64)*8);
      gll16(Al + (size_t)(row0+r)*K1 + kl + kk, sAl + (size_t)(i*256 + w*64)*8);
      gll16(Bh + (size_t)(col0+r)*K + kt + kk, sBh + (size_t)(i*256 + w*64)*8);
      gll16(Bl + (size_t)(col0+r)*K + kt + kk, sBl + (size_t)(i*256 + w*64)*8);
    }
    __syncthreads();
    #pragma unroll
    for (int kk=0;kk<64;kk+=32){
      bf16x8 avh[4], avl[4], bvh[4], bvl[4];
      #pragma unroll
      for (int m=0;m<4;m++){
        int off = (wr*64 + m*16 + (lane&15))*64 + kk + ((lane>>4)<<3);
        avh[m] = *(const bf16x8*)(sAh + off);
        avl[m] = *(const bf16x8*)(sAl + off);
      }
      #pragma unroll
      for (int n=0;n<4;n++){
        int off = (wcc*64 + n*16 + (lane&15))*64 + kk + ((lane>>4)<<3);
        bvh[n] = *(const bf16x8*)(sBh + off);
        bvl[n] = *(const bf16x8*)(sBl + off);
      }
      #pragma unroll
      for (int m=0;m<4;m++)
        #pragma unroll
        for (int n=0;n<4;n++){
          acc[m][n] = __builtin_amdgcn_mfma_f32_16x16x32_bf16(avh[m], bvh[n], acc[m][n], 0,0,0);
          acc[m][n] = __builtin_amdgcn_mfma_f32_16x16x32_bf16(avl[m], bvh[n], acc[m][n], 0,0,0);
          acc[m][n] = __builtin_amdgcn_mfma_f32_16x16x32_bf16(avh[m], bvl[n], acc[m][n], 0,0,0);
        }
    }
  }
  #pragma unroll
  for (int n=0;n<4;n++){
    int cn = col0 + wcc*64 + n*16 + (lane & 15);
    #pragma unroll
    for (int m=0;m<4;m++){
      int rm = row0 + wr*64 + m*16 + ((lane>>4)<<2);
      #pragma unroll
      for (int r=0;r<4;r++){
        float v = acc[m][n][r];
        if (ACT_TANH) v = tanhf(v);
        if (OUT_PAIR){
          bf16_t h = (bf16_t)v;
          Ch[(size_t)(rm+r)*N + cn] = h;
          Cl[(size_t)(rm+r)*N + cn] = (bf16_t)(v - (float)h);
        } else {
          Cf[(size_t)(rm+r)*N + cn] = v;
        }
      }
    }
  }
}

// ---------------- layer-0 LSTM step (A = h pair) ----------------
__global__ __launch_bounds__(256) void lstm0_step(
    const bf16_t* __restrict__ hph, const bf16_t* __restrict__ hpl,
    const bf16_t* __restrict__ whh0, const bf16_t* __restrict__ x0g,
    const float* __restrict__ cin, float* __restrict__ coutp,
    float* __restrict__ houtp, bf16_t* __restrict__ hnh, bf16_t* __restrict__ hnl)
{
  __shared__ bf16_t sAh[64*64], sAl[64*64];
  __shared__ bf16_t sB[128*64];
  __shared__ float sG[64*128];
  int tid = threadIdx.x, lane = tid&63, w = tid>>6;
  int mb = blockIdx.x >> 5, hb = blockIdx.x & 31;
  int wr = w>>1, wcc = w&1;
  f32x4 acc[2][4] = {};
  for (int kt=0; kt<1024; kt+=64){
    __syncthreads();
    #pragma unroll
    for (int i=0;i<2;i++){
      int c = i*256+tid; int r = c>>3, kk=(c&7)<<3;
      size_t src = (size_t)(mb*64+r)*1024 + kt+kk;
      gll16(hph + src, sAh + (size_t)(i*256 + w*64)*8);
      gll16(hpl + src, sAl + (size_t)(i*256 + w*64)*8);
    }
    #pragma unroll
    for (int i=0;i<4;i++){
      int c = i*256+tid; int br=c>>3, kk=(c&7)<<3;
      int gr = ((br>>5)<<10) + (hb<<5) + (br&31);
      gll16(whh0 + (size_t)gr*1024 + kt+kk, sB + (size_t)(i*256+w*64)*8);
    }
    __syncthreads();
    #pragma unroll
    for (int kk=0;kk<64;kk+=32){
      bf16x8 avh[2], avl[2], bv[4];
      #pragma unroll
      for (int m=0;m<2;m++){
        int off = (wr*32 + m*16 + (lane&15))*64 + kk + ((lane>>4)<<3);
        avh[m] = *(const bf16x8*)(sAh + off);
        avl[m] = *(const bf16x8*)(sAl + off);
      }
      #pragma unroll
      for (int n=0;n<4;n++) bv[n] = *(const bf16x8*)(sB + (wcc*64 + n*16 + (lane&15))*64 + kk + ((lane>>4)<<3));
      #pragma unroll
      for (int m=0;m<2;m++)
        #pragma unroll
        for (int n=0;n<4;n++){
          acc[m][n] = __builtin_amdgcn_mfma_f32_16x16x32_bf16(avh[m], bv[n], acc[m][n], 0,0,0);
          acc[m][n] = __builtin_amdgcn_mfma_f32_16x16x32_bf16(avl[m], bv[n], acc[m][n], 0,0,0);
        }
    }
  }
  #pragma unroll
  for (int m=0;m<2;m++)
    #pragma unroll
    for (int n=0;n<4;n++)
      #pragma unroll
      for (int r=0;r<4;r++){
        int trow = wr*32 + m*16 + ((lane>>4)<<2) + r;
        int tc   = wcc*64 + n*16 + (lane&15);
        int gcol = ((tc>>5)<<10) + (hb<<5) + (tc&31);
        float xv = (float)x0g[(size_t)(mb*64+trow)*4096 + gcol];
        sG[trow*128+tc] = acc[m][n][r] + xv;
      }
  __syncthreads();
  #pragma unroll
  for (int s=0;s<8;s++){
    int q = s*256 + tid;
    int row = q>>5, j = q&31;
    float gi = sG[row*128 + j],    gf = sG[row*128 + 32 + j];
    float gg = sG[row*128 + 64+j], go = sG[row*128 + 96 + j];
    int rg = mb*64 + row, hg = (hb<<5) + j;
    size_t idx = (size_t)rg*1024 + hg;
    float cold = cin[idx];
    float cv = sigm(gf)*cold + sigm(gi)*tanhf(gg);
    float hv = sigm(go)*tanhf(cv);
    coutp[idx] = cv; houtp[idx] = hv;
    bf16_t hh = (bf16_t)hv;
    hnh[idx] = hh; hnl[idx] = (bf16_t)(hv - (float)hh);
  }
}

// ---------------- layer-1 LSTM step (A = [h0cur | h1prev] pairs) ----------------
__global__ __launch_bounds__(256) void lstm1_step(
    const bf16_t* __restrict__ h0h, const bf16_t* __restrict__ h0l,
    const bf16_t* __restrict__ h1h, const bf16_t* __restrict__ h1l,
    const bf16_t* __restrict__ wih1, const bf16_t* __restrict__ whh1,
    const float* __restrict__ bias1, const float* __restrict__ cin,
    float* __restrict__ coutp, float* __restrict__ houtp,
    bf16_t* __restrict__ hnh, bf16_t* __restrict__ hnl)
{
  __shared__ bf16_t sAh[64*64], sAl[64*64];
  __shared__ bf16_t sB[128*64];
  __shared__ float sG[64*128];
  int tid = threadIdx.x, lane = tid&63, w = tid>>6;
  int mb = blockIdx.x >> 5, hb = blockIdx.x & 31;
  int wr = w>>1, wcc = w&1;
  f32x4 acc[2][4] = {};
  for (int kt=0; kt<2048; kt+=64){
    const bf16_t *Ah, *Al, *Bp; int kl;
    if (kt < 1024){ Ah=h0h; Al=h0l; Bp=wih1; kl=kt; }
    else          { Ah=h1h; Al=h1l; Bp=whh1; kl=kt-1024; }
    __syncthreads();
    #pragma unroll
    for (int i=0;i<2;i++){
      int c = i*256+tid; int r = c>>3, kk=(c&7)<<3;
      size_t src = (size_t)(mb*64+r)*1024 + kl+kk;
      gll16(Ah + src, sAh + (size_t)(i*256 + w*64)*8);
      gll16(Al + src, sAl + (size_t)(i*256 + w*64)*8);
    }
    #pragma unroll
    for (int i=0;i<4;i++){
      int c = i*256+tid; int br=c>>3, kk=(c&7)<<3;
      int gr = ((br>>5)<<10) + (hb<<5) + (br&31);
      gll16(Bp + (size_t)gr*1024 + kl+kk, sB + (size_t)(i*256+w*64)*8);
    }
    __syncthreads();
    #pragma unroll
    for (int kk=0;kk<64;kk+=32){
      bf16x8 avh[2], avl[2], bv[4];
      #pragma unroll
      for (int m=0;m<2;m++){
        int off = (wr*32 + m*16 + (lane&15))*64 + kk + ((lane>>4)<<3);
        avh[m] = *(const bf16x8*)(sAh + off);
        avl[m] = *(const bf16x8*)(sAl + off);
      }
      #pragma unroll
      for (int n=0;n<4;n++) bv[n] = *(const bf16x8*)(sB + (wcc*64 + n*16 + (lane&15))*64 + kk + ((lane>>4)<<3));
      #pragma unroll
      for (int m=0;m<2;m++)
        #pragma unroll
        for (int n=0;n<4;n++){
          acc[m][n] = __builtin_amdgcn_mfma_f32_16x16x32_bf16(avh[m], bv[n], acc[m][n], 0,0,0);
          acc[m][n] = __builtin_amdgcn_mfma_f32_16x16x32_bf16(avl[m], bv[n], acc[m][n], 0,0,0);
        }
    }
  }
  #pragma unroll
  for (int m=0;m<2;m++)
    #pragma unroll
    for (int n=0;n<4;n++)
      #pragma unroll
      for (int r=0;r<4;r++){
        int trow = wr*32 + m*16 + ((lane>>4)<<2) + r;
        int tc   = wcc*64 + n*16 + (lane&15);
        int gcol = ((tc>>5)<<10) + (hb<<5) + (tc&31);
        sG[trow*128+tc] = acc[m][n][r] + bias1[gcol];
      }
  __syncthreads();
  #pragma unroll
  for (int s=0;s<8;s++){
    int q = s*256 + tid;
    int row = q>>5, j = q&31;
    float gi = sG[row*128 + j],    gf = sG[row*128 + 32 + j];
    float gg = sG[row*128 + 64+j], go = sG[row*128 + 96 + j];
    int rg = mb*64 + row, hg = (hb<<5) + j;
    size_t idx = (size_t)rg*1024 + hg;
    float cold = cin[idx];
    float cv = sigm(gf)*cold + sigm(gi)*tanhf(gg);
    float hv = sigm(go)*tanhf(cv);
    coutp[idx] = cv; houtp[idx] = hv;
    bf16_t hh = (bf16_t)hv;
    hnh[idx] = hh; hnl[idx] = (bf16_t)(hv - (float)hh);
  }
}

// ---------------- scores + softmax (per batch row b), post-loop ----------------
// scores[t,s] = h1[t+1,b,:] . ctxW[b,s,:], 3-combo split MFMA; softmax in-kernel.
__global__ __launch_bounds__(256) void attn_sm(
    const bf16_t* __restrict__ h1h, const bf16_t* __restrict__ h1l,
    const bf16_t* __restrict__ cwh, const bf16_t* __restrict__ cwl,
    float* __restrict__ a_all, float* __restrict__ outA)
{
  __shared__ bf16_t sAh[64*64], sAl[64*64];
  __shared__ bf16_t sBh[128*64], sBl[128*64];
  __shared__ float sS[64*128];
  int b = blockIdx.x;
  int tid = threadIdx.x, lane = tid&63, w = tid>>6;
  int wr = w>>1, wcc = w&1;
  f32x4 acc[2][4] = {};
  for (int kt=0; kt<1024; kt+=64){
    __syncthreads();
    #pragma unroll
    for (int i=0;i<2;i++){
      int c = i*256+tid; int r = c>>3, kk=(c&7)<<3;
      size_t src = (size_t)(r+1)*131072 + (size_t)b*1024 + kt+kk;
      gll16(h1h + src, sAh + (size_t)(i*256 + w*64)*8);
      gll16(h1l + src, sAl + (size_t)(i*256 + w*64)*8);
    }
    #pragma unroll
    for (int i=0;i<4;i++){
      int c = i*256+tid; int br=c>>3, kk=(c&7)<<3;
      size_t src = ((size_t)b*128 + br)*1024 + kt+kk;
      gll16(cwh + src, sBh + (size_t)(i*256+w*64)*8);
      gll16(cwl + src, sBl + (size_t)(i*256+w*64)*8);
    }
    __syncthreads();
    #pragma unroll
    for (int kk=0;kk<64;kk+=32){
      bf16x8 avh[2], avl[2], bvh[4], bvl[4];
      #pragma unroll
      for (int m=0;m<2;m++){
        int off = (wr*32 + m*16 + (lane&15))*64 + kk + ((lane>>4)<<3);
        avh[m] = *(const bf16x8*)(sAh + off);
        avl[m] = *(const bf16x8*)(sAl + off);
      }
      #pragma unroll
      for (int n=0;n<4;n++){
        int off = (wcc*64 + n*16 + (lane&15))*64 + kk + ((lane>>4)<<3);
        bvh[n] = *(const bf16x8*)(sBh + off);
        bvl[n] = *(const bf16x8*)(sBl + off);
      }
      #pragma unroll
      for (int m=0;m<2;m++)
        #pragma unroll
        for (int n=0;n<4;n++){
          acc[m][n] = __builtin_amdgcn_mfma_f32_16x16x32_bf16(avh[m], bvh[n], acc[m][n], 0,0,0);
          acc[m][n] = __builtin_amdgcn_mfma_f32_16x16x32_bf16(avl[m], bvh[n], acc[m][n], 0,0,0);
          acc[m][n] = __builtin_amdgcn_mfma_f32_16x16x32_bf16(avh[m], bvl[n], acc[m][n], 0,0,0);
        }
    }
  }
  #pragma unroll
  for (int m=0;m<2;m++)
    #pragma unroll
    for (int n=0;n<4;n++)
      #pragma unroll
      for (int r=0;r<4;r++){
        int trow = wr*32 + m*16 + ((lane>>4)<<2) + r;
        int tc   = wcc*64 + n*16 + (lane&15);
        sS[trow*128+tc] = acc[m][n][r];
      }
  __syncthreads();
  for (int i=0;i<16;i++){
    int r = w*16 + i;
    float v0 = sS[r*128 + lane], v1 = sS[r*128 + 64 + lane];
    float mx = fmaxf(v0, v1);
    #pragma unroll
    for (int off=32; off; off>>=1) mx = fmaxf(mx, __shfl_xor(mx, off));
    float e0 = expf(v0-mx), e1 = expf(v1-mx);
    float sm = e0+e1;
    #pragma unroll
    for (int off=32; off; off>>=1) sm += __shfl_xor(sm, off);
    float inv = 1.f/sm;
    size_t base = ((size_t)r*128 + b)*128;
    a_all[base + lane]      = e0*inv;
    a_all[base + 64 + lane] = e1*inv;
    if (r == 63){
      outA[(size_t)b*128 + lane]      = e0*inv;
      outA[(size_t)b*128 + 64 + lane] = e1*inv;
    }
  }
}

// ---------------- wc (fp32 VALU), post-loop: wc[t,b,:] = sum_s a[t,b,s]*ctx[b,s,:] ----
__global__ __launch_bounds__(256) void wc_all(
    const float* __restrict__ a_all, const float* __restrict__ ctx,
    bf16_t* __restrict__ wch, bf16_t* __restrict__ wcl)
{
  int bid = blockIdx.x;
  int b = bid & 127, tg = bid >> 7;  // tg 0..3, 16 t each
  int tid = threadIdx.x;
  __shared__ float sa[16][128];
  int t0 = tg*16;
  #pragma unroll
  for (int i=0;i<8;i++){
    int q = i*256 + tid;
    int ti = q >> 7, s = q & 127;
    sa[ti][s] = a_all[((size_t)(t0+ti)*128 + b)*128 + s];
  }
  __syncthreads();
  f32x4 acc[16];
  #pragma unroll
  for (int i=0;i<16;i++) acc[i] = f32x4{0,0,0,0};
  const float* cb = ctx + (size_t)b*128*1024 + tid*4;
  for (int s=0;s<128;s++){
    f32x4 c = *(const f32x4*)(cb + (size_t)s*1024);
    #pragma unroll
    for (int ti=0;ti<16;ti++){
      float av = sa[ti][s];
      acc[ti] += av * c;
    }
  }
  #pragma unroll
  for (int ti=0;ti<16;ti++){
    size_t m = (size_t)(t0+ti)*128 + b;
    bf16x4 h, l;
    #pragma unroll
    for (int j=0;j<4;j++){
      float v = acc[ti][j];
      h[j] = (bf16_t)v; l[j] = (bf16_t)(v - (float)h[j]);
    }
    *(bf16x4*)(wch + m*1024 + tid*4) = h;
    *(bf16x4*)(wcl + m*1024 + tid*4) = l;
  }
}

// ---------------- host ----------------
extern "C" void kernel_launch(void* const* d_in, const int* in_sizes, int n_in,
                              void* d_out, int out_size, void* d_ws, size_t ws_size,
                              hipStream_t stream)
{
  (void)in_sizes; (void)n_in; (void)out_size; (void)ws_size;
  const int TT=64, BB=128, H=1024, G=4096, BH=128*1024;

  const int*   tok  = (const int*)d_in[0];
  const float* h0   = (const float*)d_in[1];
  const float* c0   = (const float*)d_in[2];
  const float* ctx  = (const float*)d_in[3];
  const float* embW = (const float*)d_in[5];
  const float* wih  = (const float*)d_in[6];
  const float* whh  = (const float*)d_in[7];
  const float* bih  = (const float*)d_in[8];
  const float* bhh  = (const float*)d_in[9];
  const float* Win  = (const float*)d_in[10];
  const float* Wout = (const float*)d_in[11];

  float* outY = (float*)d_out;                      // [T,B,H]
  float* outH = outY + (size_t)TT*BB*H;             // [2,B,H]
  float* outC = outH + (size_t)2*BH;                // [2,B,H]
  float* outA = outC + (size_t)2*BH;                // [B,S]

  char* ws = (char*)d_ws;
  size_t o = 0;
  auto carve = [&](size_t bytes)->char* {
    char* p = ws + o; o += (bytes + 255) & ~(size_t)255; return p;
  };
  bf16_t* wihB  = (bf16_t*)carve((size_t)2*G*H*2);       // 16MB
  bf16_t* whhB  = (bf16_t*)carve((size_t)2*G*H*2);       // 16MB
  bf16_t* woutH = (bf16_t*)carve((size_t)H*2*H*2);       // 4MB
  bf16_t* woutL = (bf16_t*)carve((size_t)H*2*H*2);       // 4MB
  bf16_t* winTh = (bf16_t*)carve((size_t)H*H*2);         // 2MB
  bf16_t* winTl = (bf16_t*)carve((size_t)H*H*2);         // 2MB
  bf16_t* ctxh  = (bf16_t*)carve((size_t)BB*128*H*2);    // 32MB (post-loop: wch)
  bf16_t* ctxl  = (bf16_t*)carve((size_t)BB*128*H*2);    // 32MB (post-loop: wcl)
  bf16_t* cwh   = (bf16_t*)carve((size_t)BB*128*H*2);    // 32MB (pre: xemb overlays)
  bf16_t* cwl   = (bf16_t*)carve((size_t)BB*128*H*2);    // 32MB
  bf16_t* x0g   = (bf16_t*)carve((size_t)TT*BB*G*2);     // 64MB
  bf16_t* h0rh  = (bf16_t*)carve((size_t)2*BH*2);        // ring, 2 slots
  bf16_t* h0rl  = (bf16_t*)carve((size_t)2*BH*2);
  bf16_t* h1h   = (bf16_t*)carve((size_t)(TT+1)*BH*2);   // 17MB history
  bf16_t* h1l   = (bf16_t*)carve((size_t)(TT+1)*BH*2);   // 17MB
  float*  a_all = (float*)carve((size_t)TT*BB*128*4);    // 4MB
  float*  biasF = (float*)carve((size_t)2*G*4);

  bf16_t* xemb = cwh;            // overlays ctxW-hi (dead until ctxW GEMM)
  bf16_t* wch  = ctxh;           // overlays ctx pair (dead post-loop)
  bf16_t* wcl  = ctxl;

  // ---- prep ----
  f2b<<<(2*G*H)/1024, 256, 0, stream>>>(wih, wihB, 2*G*H);
  f2b<<<(2*G*H)/1024, 256, 0, stream>>>(whh, whhB, 2*G*H);
  f2b_pair<<<(H*2*H)/1024, 256, 0, stream>>>(Wout, woutH, woutL, H*2*H);
  f2b_pair<<<(BB*128*H)/1024, 256, 0, stream>>>(ctx, ctxh, ctxl, BB*128*H);
  f2b_pair<<<BH/1024, 256, 0, stream>>>(h0, h0rh, h0rl, BH);
  f2b_pair<<<BH/1024, 256, 0, stream>>>(h0 + BH, h1h, h1l, BH);
  transWin<<<1024, 256, 0, stream>>>(Win, winTh, winTl);
  bias_combine<<<(2*G)/256, 256, 0, stream>>>(bih, bhh, biasF, 2*G);
  embed_gather<<<TT*BB, 256, 0, stream>>>(tok, embW, xemb);

  // ---- one-time GEMMs ----
  // x0g = xemb @ wih0^T + bias0  (bf16 out)
  gemm_bt<<<(TT*BB/128)*(G/128), 256, 0, stream>>>(xemb, wihB, biasF, x0g, TT*BB, G, H, G/128);
  // ctxW = ctx @ Win^T (split, pair out) -- overwrites xemb region (dead now)
  gemm_split<0,1><<<(BB*128/128)*(H/128), 256, 0, stream>>>(
      ctxh, ctxl, ctxh, ctxl, H, winTh, winTl,
      nullptr, cwh, cwl, BB*128, H, H, H/128);

  // ---- sequential loop: 2 kernels per step ----
  for (int t=0; t<TT; ++t){
    int s0 = t & 1, s1 = (t+1) & 1;
    const float* cin0 = t ? (const float*)outC : c0;
    lstm0_step<<<64, 256, 0, stream>>>(
        h0rh + (size_t)s0*BH, h0rl + (size_t)s0*BH, whhB, x0g + (size_t)t*BB*G,
        cin0, outC, outH, h0rh + (size_t)s1*BH, h0rl + (size_t)s1*BH);

    const float* cin1 = t ? (const float*)(outC + BH) : (c0 + BH);
    lstm1_step<<<64, 256, 0, stream>>>(
        h0rh + (size_t)s1*BH, h0rl + (size_t)s1*BH,
        h1h + (size_t)t*BH, h1l + (size_t)t*BH,
        wihB + (size_t)G*H, whhB + (size_t)G*H, biasF + G, cin1,
        outC + BH, outH + BH,
        h1h + (size_t)(t+1)*BH, h1l + (size_t)(t+1)*BH);
  }

  // ---- post-loop attention ----
  attn_sm<<<BB, 256, 0, stream>>>(h1h, h1l, cwh, cwl, a_all, outA);
  wc_all<<<BB*4, 256, 0, stream>>>(a_all, ctx, wch, wcl);

  // outY = tanh([wc | h1] @ Wout^T), split GEMM, fp32 out
  gemm_split<1,0><<<(TT*BB/128)*(H/128), 256, 0, stream>>>(
      wch, wcl, h1h + BH, h1l + BH, H, woutH, woutL,
      outY, nullptr, nullptr, TT*BB, H, 2*H, H/128);
}